// Round 2
// baseline (1405.112 us; speedup 1.0000x reference)
//
#include <hip/hip_runtime.h>
#include <math.h>

#define NN 768
#define CS 384
#define CZ 128
#define CH 16
#define HH 12
#define PQ 4
#define PV 8
#define OUTIN 2112

#define SC_QK 0.14433756729740643f   // sqrt(1/(3*16))
#define SC_B  0.57735026918962576f   // sqrt(1/3)
#define SC_HW 0.13608276348795434f   // sqrt(2/(27*4))

// ---------------- Kernel A: input projections (s @ W.T + b) ----------------
__global__ __launch_bounds__(256) void kproj(
    const float* __restrict__ s,
    const float* __restrict__ Wq,  const float* __restrict__ bq,
    const float* __restrict__ Wkv, const float* __restrict__ bkv,
    const float* __restrict__ Wqp, const float* __restrict__ bqp,
    const float* __restrict__ Wkvp,const float* __restrict__ bkvp,
    float* __restrict__ q, float* __restrict__ kT, float* __restrict__ vall,
    float* __restrict__ qpr, float* __restrict__ kvpr)
{
    __shared__ float s_lds[8*384];
    int n0 = blockIdx.x * 8;
    int t = threadIdx.x;
    for (int idx = t; idx < 8*384; idx += 256)
        s_lds[idx] = s[(n0 + idx/384)*384 + (idx%384)];
    __syncthreads();

    int o = blockIdx.y * 128 + (t & 127);
    int ng = t >> 7;
    const float* wrow; float bias;
    if (o < 192)      { wrow = Wq   + o*384;       bias = bq[o]; }
    else if (o < 576) { wrow = Wkv  + (o-192)*384; bias = bkv[o-192]; }
    else if (o < 720) { wrow = Wqp  + (o-576)*384; bias = bqp[o-576]; }
    else              { wrow = Wkvp + (o-720)*384; bias = bkvp[o-720]; }

    float acc[4] = {bias, bias, bias, bias};
    const float4* wr4 = reinterpret_cast<const float4*>(wrow);
    for (int c4 = 0; c4 < 96; ++c4) {
        float4 w = wr4[c4];
        #pragma unroll
        for (int nn = 0; nn < 4; ++nn) {
            const float* sr = &s_lds[(ng*4+nn)*384 + c4*4];
            acc[nn] = fmaf(w.x, sr[0], acc[nn]);
            acc[nn] = fmaf(w.y, sr[1], acc[nn]);
            acc[nn] = fmaf(w.z, sr[2], acc[nn]);
            acc[nn] = fmaf(w.w, sr[3], acc[nn]);
        }
    }
    #pragma unroll
    for (int nn = 0; nn < 4; ++nn) {
        int n = n0 + ng*4 + nn;
        float v = acc[nn];
        if (o < 192)      q[n*192 + o] = v;
        else if (o < 576) {
            int oo = o - 192, h = oo >> 5, cc = oo & 31;
            if (cc < 16) kT[(h*NN + n)*16 + cc] = v;
            else         vall[(size_t)n*480 + h*40 + (cc-16)] = v;
        }
        else if (o < 720) qpr[n*144 + (o-576)] = v;
        else              kvpr[n*432 + (o-720)] = v;
    }
}

// ---------------- Kernel B: apply frames (rot, trans) to points ----------------
__global__ __launch_bounds__(192) void krot(
    const float* __restrict__ rot, const float* __restrict__ trans,
    const float* __restrict__ qpr, const float* __restrict__ kvpr,
    float* __restrict__ qp, float* __restrict__ kpT, float* __restrict__ vall)
{
    int n = blockIdx.x;
    __shared__ float R[9], T[3];
    int t = threadIdx.x;
    if (t < 9) R[t] = rot[n*9 + t];
    if (t < 3) T[t] = trans[n*3 + t];
    __syncthreads();

    const float* src = (t < 48) ? (qpr + n*144 + t*3) : (kvpr + n*432 + (t-48)*3);
    float x = src[0], y = src[1], z = src[2];
    float wx = R[0]*x + R[1]*y + R[2]*z + T[0];
    float wy = R[3]*x + R[4]*y + R[5]*z + T[1];
    float wz = R[6]*x + R[7]*y + R[8]*z + T[2];
    if (t < 48) {
        float* d = qp + n*144 + t*3;
        d[0]=wx; d[1]=wy; d[2]=wz;
    } else {
        int pi = t - 48, h = pi/12, pp = pi%12;
        float* d = (pp < 4) ? (kpT + (h*NN+n)*12 + pp*3)
                            : (vall + (size_t)n*480 + h*40 + 16 + (pp-4)*3);
        d[0]=wx; d[1]=wy; d[2]=wz;
    }
}

// ---------------- Kernel C: fused attention, LDS-staged z ----------------
// One block per query row i. 4 waves x 3 heads (phase 1 + phase 2).
// z tile [64 j][128 c] staged in LDS with XOR-swizzle via pre-swizzled
// global source addresses (global_load_lds writes linearly).
__global__ __launch_bounds__(256, 3) void kattn(
    const float* __restrict__ z, const float* __restrict__ mask,
    const float* __restrict__ Wb, const float* __restrict__ bb,
    const float* __restrict__ head_w,
    const float* __restrict__ rot, const float* __restrict__ trans,
    const float* __restrict__ q, const float* __restrict__ kT,
    const float* __restrict__ kpT, const float* __restrict__ vall,
    const float* __restrict__ qp, float* __restrict__ cat)
{
    __shared__ float4 z_lds4[64][32];          // 32 KB, swizzled: [j][c4 ^ (j&7)]
    __shared__ float4 wb4[12*32];              // 6 KB
    __shared__ float  p_lds[12][68];           // pad 68: write 2-way free, b128-aligned rows
    __shared__ float  q_lds[192], qp_lds[144];
    __shared__ float  corr_lds[12], lrun_lds[12], hw_lds[12], bb_lds[12];
    __shared__ float  R[9], T[3];
    __shared__ float  opt_lds[12][24];

    const int i = blockIdx.x;
    const int t = threadIdx.x;
    const int w = t >> 6, l = t & 63;
    const int h0 = w * 3;

    for (int idx = t; idx < 192; idx += 256) q_lds[idx]  = q[i*192 + idx];
    for (int idx = t; idx < 144; idx += 256) qp_lds[idx] = qp[i*144 + idx];
    for (int idx = t; idx < 384; idx += 256) wb4[idx] = reinterpret_cast<const float4*>(Wb)[idx];
    if (t < 12) { hw_lds[t] = log1pf(expf(head_w[t])) * SC_HW; bb_lds[t] = bb[t]; }
    if (t < 9) R[t] = rot[i*9 + t];
    if (t < 3) T[t] = trans[i*3 + t];

    const size_t zrow = (size_t)i * NN * CZ;

    // ---- stage tile 0 (swizzled source, linear LDS dest) ----
    #pragma unroll
    for (int k = 0; k < 8; ++k) {
        int s4 = (w*8 + k)*64 + l;            // flat float4-slot 0..2047
        int j  = s4 >> 5, sl = s4 & 31;
        const float* g = z + zrow + (size_t)j*CZ + (((sl ^ (j & 7)) << 2));
        __builtin_amdgcn_global_load_lds(
            (const __attribute__((address_space(1))) void*)g,
            (__attribute__((address_space(3))) void*)((char*)&z_lds4[0][0] + (size_t)s4*16),
            16, 0, 0);
    }

    float m_run[3] = {-1e30f, -1e30f, -1e30f};
    float l_run[3] = {0.f, 0.f, 0.f};
    float2 opz[3]  = {{0.f,0.f},{0.f,0.f},{0.f,0.f}};
    float2 ovv     = {0.f, 0.f};
    const int bh = t / 20, be = (t % 20) * 2;  // phase-2b mapping (t<240)
    const float maski = mask[i];
    float hwv[3], bbv[3];

    __syncthreads();   // covers init LDS writes before first read of hw/bb
    #pragma unroll
    for (int hi = 0; hi < 3; ++hi) { hwv[hi] = hw_lds[h0+hi]; bbv[hi] = bb_lds[h0+hi]; }

    for (int tile = 0; tile < 12; ++tile) {
        const int j0 = tile * 64;
        if (tile) __syncthreads();   // A: stage of this tile complete, p_lds free
        const int j = j0 + l;

        // ---- phase 1: logits for 3 heads at column j = j0 + l ----
        float qk[3], d2[3];
        #pragma unroll
        for (int hi = 0; hi < 3; ++hi) {
            const float4* kr = reinterpret_cast<const float4*>(kT) + ((size_t)((h0+hi)*NN + j) << 2);
            float4 k0 = kr[0], k1 = kr[1], k2 = kr[2], k3 = kr[3];
            const float4* qr = reinterpret_cast<const float4*>(q_lds + (h0+hi)*16);
            float4 q0 = qr[0], q1 = qr[1], q2 = qr[2], q3 = qr[3];
            float acc = k0.x*q0.x + k0.y*q0.y + k0.z*q0.z + k0.w*q0.w;
            acc = fmaf(k1.x, q1.x, acc); acc = fmaf(k1.y, q1.y, acc);
            acc = fmaf(k1.z, q1.z, acc); acc = fmaf(k1.w, q1.w, acc);
            acc = fmaf(k2.x, q2.x, acc); acc = fmaf(k2.y, q2.y, acc);
            acc = fmaf(k2.z, q2.z, acc); acc = fmaf(k2.w, q2.w, acc);
            acc = fmaf(k3.x, q3.x, acc); acc = fmaf(k3.y, q3.y, acc);
            acc = fmaf(k3.z, q3.z, acc); acc = fmaf(k3.w, q3.w, acc);
            qk[hi] = acc;

            const float4* pr = reinterpret_cast<const float4*>(kpT) + (size_t)((h0+hi)*NN + j)*3;
            float4 a0 = pr[0], a1 = pr[1], a2 = pr[2];
            const float* qpv = qp_lds + (h0+hi)*12;
            float d, s2;
            d = qpv[0]  - a0.x; s2 = d*d;
            d = qpv[1]  - a0.y; s2 = fmaf(d,d,s2);
            d = qpv[2]  - a0.z; s2 = fmaf(d,d,s2);
            d = qpv[3]  - a0.w; s2 = fmaf(d,d,s2);
            d = qpv[4]  - a1.x; s2 = fmaf(d,d,s2);
            d = qpv[5]  - a1.y; s2 = fmaf(d,d,s2);
            d = qpv[6]  - a1.z; s2 = fmaf(d,d,s2);
            d = qpv[7]  - a1.w; s2 = fmaf(d,d,s2);
            d = qpv[8]  - a2.x; s2 = fmaf(d,d,s2);
            d = qpv[9]  - a2.y; s2 = fmaf(d,d,s2);
            d = qpv[10] - a2.z; s2 = fmaf(d,d,s2);
            d = qpv[11] - a2.w; s2 = fmaf(d,d,s2);
            d2[hi] = s2;
        }

        // bias: z row (from swizzled LDS) dot Wb rows (broadcast)
        float b0 = bbv[0], b1 = bbv[1], b2 = bbv[2];
        const int sw = l & 7;
        #pragma unroll 4
        for (int c4 = 0; c4 < 32; ++c4) {
            float4 zv = z_lds4[l][c4 ^ sw];
            float4 w0 = wb4[(h0+0)*32 + c4];
            float4 w1 = wb4[(h0+1)*32 + c4];
            float4 w2 = wb4[(h0+2)*32 + c4];
            b0 = fmaf(zv.x,w0.x,b0); b0 = fmaf(zv.y,w0.y,b0); b0 = fmaf(zv.z,w0.z,b0); b0 = fmaf(zv.w,w0.w,b0);
            b1 = fmaf(zv.x,w1.x,b1); b1 = fmaf(zv.y,w1.y,b1); b1 = fmaf(zv.z,w1.z,b1); b1 = fmaf(zv.w,w1.w,b1);
            b2 = fmaf(zv.x,w2.x,b2); b2 = fmaf(zv.y,w2.y,b2); b2 = fmaf(zv.z,w2.z,b2); b2 = fmaf(zv.w,w2.w,b2);
        }

        const float mterm = 1e9f * (maski * mask[j] - 1.0f);
        float lg[3];
        lg[0] = fmaf(qk[0], SC_QK, fmaf(b0, SC_B, -0.5f*hwv[0]*d2[0])) + mterm;
        lg[1] = fmaf(qk[1], SC_QK, fmaf(b1, SC_B, -0.5f*hwv[1]*d2[1])) + mterm;
        lg[2] = fmaf(qk[2], SC_QK, fmaf(b2, SC_B, -0.5f*hwv[2]*d2[2])) + mterm;

        // ---- online softmax (3 heads interleaved) ----
        float mx0 = lg[0], mx1 = lg[1], mx2 = lg[2];
        #pragma unroll
        for (int off = 32; off >= 1; off >>= 1) {
            mx0 = fmaxf(mx0, __shfl_xor(mx0, off, 64));
            mx1 = fmaxf(mx1, __shfl_xor(mx1, off, 64));
            mx2 = fmaxf(mx2, __shfl_xor(mx2, off, 64));
        }
        float mn0 = fmaxf(m_run[0], mx0), mn1 = fmaxf(m_run[1], mx1), mn2 = fmaxf(m_run[2], mx2);
        float cr0 = __expf(m_run[0]-mn0), cr1 = __expf(m_run[1]-mn1), cr2 = __expf(m_run[2]-mn2);
        float p0 = __expf(lg[0]-mn0), p1 = __expf(lg[1]-mn1), p2 = __expf(lg[2]-mn2);
        float s0 = p0, s1 = p1, s2s = p2;
        #pragma unroll
        for (int off = 32; off >= 1; off >>= 1) {
            s0  += __shfl_xor(s0, off, 64);
            s1  += __shfl_xor(s1, off, 64);
            s2s += __shfl_xor(s2s, off, 64);
        }
        l_run[0] = fmaf(l_run[0], cr0, s0);
        l_run[1] = fmaf(l_run[1], cr1, s1);
        l_run[2] = fmaf(l_run[2], cr2, s2s);
        m_run[0] = mn0; m_run[1] = mn1; m_run[2] = mn2;

        p_lds[h0+0][l] = p0;
        p_lds[h0+1][l] = p1;
        p_lds[h0+2][l] = p2;
        if (l == 0) { corr_lds[h0+0] = cr0; corr_lds[h0+1] = cr1; corr_lds[h0+2] = cr2; }

        opz[0].x *= cr0; opz[0].y *= cr0;
        opz[1].x *= cr1; opz[1].y *= cr1;
        opz[2].x *= cr2; opz[2].y *= cr2;

        __syncthreads();   // B: p_lds / corr_lds visible

        // ---- phase 2: o_pair accumulate. lane = float2-column c2 = l ----
        const int c2h = l >> 1, c2lo = (l & 1) * 2;
        for (int j4 = 0; j4 < 16; ++j4) {
            float4 pA = *reinterpret_cast<const float4*>(&p_lds[h0+0][j4<<2]);
            float4 pB = *reinterpret_cast<const float4*>(&p_lds[h0+1][j4<<2]);
            float4 pC = *reinterpret_cast<const float4*>(&p_lds[h0+2][j4<<2]);
            #pragma unroll
            for (int u = 0; u < 4; ++u) {
                const int jl = (j4 << 2) | u;
                const float* zp = reinterpret_cast<const float*>(&z_lds4[jl][c2h ^ (jl & 7)]) + c2lo;
                float zx = zp[0], zy = zp[1];
                float fA = reinterpret_cast<const float*>(&pA)[u];
                float fB = reinterpret_cast<const float*>(&pB)[u];
                float fC = reinterpret_cast<const float*>(&pC)[u];
                opz[0].x = fmaf(fA, zx, opz[0].x); opz[0].y = fmaf(fA, zy, opz[0].y);
                opz[1].x = fmaf(fB, zx, opz[1].x); opz[1].y = fmaf(fB, zy, opz[1].y);
                opz[2].x = fmaf(fC, zx, opz[2].x); opz[2].y = fmaf(fC, zy, opz[2].y);
            }
        }

        __syncthreads();   // C: z_lds reads done -> safe to overwrite

        // ---- prefetch next z tile (async; drains at barrier A) ----
        if (tile + 1 < 12) {
            const int jn0 = (tile + 1) * 64;
            #pragma unroll
            for (int k = 0; k < 8; ++k) {
                int s4 = (w*8 + k)*64 + l;
                int jj = s4 >> 5, sl = s4 & 31;
                const float* g = z + zrow + (size_t)(jn0 + jj)*CZ + (((sl ^ (jj & 7)) << 2));
                __builtin_amdgcn_global_load_lds(
                    (const __attribute__((address_space(1))) void*)g,
                    (__attribute__((address_space(3))) void*)((char*)&z_lds4[0][0] + (size_t)s4*16),
                    16, 0, 0);
            }
        }

        // ---- phase 2b: o (v) + o_pt (v_pts) accumulate, overlaps prefetch ----
        if (t < 240) {
            float cb = corr_lds[bh];
            ovv.x *= cb; ovv.y *= cb;
            const float* vp = vall + (size_t)j0*480 + bh*40 + be;
            #pragma unroll 4
            for (int jl = 0; jl < 64; ++jl) {
                float2 vv = *reinterpret_cast<const float2*>(vp + (size_t)jl*480);
                float pj = p_lds[bh][jl];
                ovv.x = fmaf(pj, vv.x, ovv.x);
                ovv.y = fmaf(pj, vv.y, ovv.y);
            }
        }
    }

    // ---- finalize ----
    float* crow = cat + (size_t)i * OUTIN;
    if (l == 0) {
        lrun_lds[h0+0] = l_run[0]; lrun_lds[h0+1] = l_run[1]; lrun_lds[h0+2] = l_run[2];
    }
    #pragma unroll
    for (int hi = 0; hi < 3; ++hi) {
        float inv = 1.0f / l_run[hi];
        float2 o2 = { opz[hi].x * inv, opz[hi].y * inv };
        *reinterpret_cast<float2*>(&crow[576 + (h0+hi)*128 + 2*l]) = o2;
    }
    __syncthreads();
    if (t < 240) {
        float invb = 1.0f / lrun_lds[bh];
        float a0 = ovv.x * invb, a1 = ovv.y * invb;
        if (be < 16) { crow[bh*16 + be] = a0; crow[bh*16 + be + 1] = a1; }
        else         { opt_lds[bh][be-16] = a0; opt_lds[bh][be-15] = a1; }
    }
    __syncthreads();
    if (t < 96) {
        int h = t >> 3, p = t & 7;
        float wx = opt_lds[h][p*3+0] - T[0];
        float wy = opt_lds[h][p*3+1] - T[1];
        float wz = opt_lds[h][p*3+2] - T[2];
        crow[192 + 0*96 + h*8 + p] = R[0]*wx + R[3]*wy + R[6]*wz;
        crow[192 + 1*96 + h*8 + p] = R[1]*wx + R[4]*wy + R[7]*wz;
        crow[192 + 2*96 + h*8 + p] = R[2]*wx + R[5]*wy + R[8]*wz;
        crow[480 + h*8 + p] = sqrtf(fmaf(wx,wx,fmaf(wy,wy,wz*wz)) + 1e-8f);
    }
}

// ---------------- Kernel D: output projection (cat @ Wout.T + bout) ----------------
__global__ __launch_bounds__(256) void kout(
    const float* __restrict__ cat, const float* __restrict__ Wout,
    const float* __restrict__ bout, float* __restrict__ out)
{
    __shared__ float c_lds[8*528];
    int n0 = blockIdx.x * 8;
    int t = threadIdx.x;
    int o = blockIdx.y * 128 + (t & 127);
    int ng = t >> 7;
    float b = bout[o];
    float acc[4] = {b, b, b, b};
    for (int ch = 0; ch < 4; ++ch) {
        __syncthreads();
        for (int idx = t; idx < 8*528; idx += 256)
            c_lds[idx] = cat[(size_t)(n0 + idx/528)*OUTIN + ch*528 + (idx%528)];
        __syncthreads();
        const float4* wr = reinterpret_cast<const float4*>(Wout + (size_t)o*OUTIN + ch*528);
        for (int c4 = 0; c4 < 132; ++c4) {
            float4 wv = wr[c4];
            #pragma unroll
            for (int nn = 0; nn < 4; ++nn) {
                const float* cr = &c_lds[(ng*4+nn)*528 + c4*4];
                acc[nn] = fmaf(wv.x, cr[0], acc[nn]);
                acc[nn] = fmaf(wv.y, cr[1], acc[nn]);
                acc[nn] = fmaf(wv.z, cr[2], acc[nn]);
                acc[nn] = fmaf(wv.w, cr[3], acc[nn]);
            }
        }
    }
    #pragma unroll
    for (int nn = 0; nn < 4; ++nn)
        out[(size_t)(n0 + ng*4 + nn)*384 + o] = acc[nn];
}

extern "C" void kernel_launch(void* const* d_in, const int* in_sizes, int n_in,
                              void* d_out, int out_size, void* d_ws, size_t ws_size,
                              hipStream_t stream) {
    const float* s      = (const float*)d_in[0];
    const float* z      = (const float*)d_in[1];
    const float* rot    = (const float*)d_in[2];
    const float* trans  = (const float*)d_in[3];
    const float* mask   = (const float*)d_in[4];
    const float* Wq     = (const float*)d_in[5];
    const float* bq     = (const float*)d_in[6];
    const float* Wkv    = (const float*)d_in[7];
    const float* bkv    = (const float*)d_in[8];
    const float* Wqp    = (const float*)d_in[9];
    const float* bqp    = (const float*)d_in[10];
    const float* Wkvp   = (const float*)d_in[11];
    const float* bkvp   = (const float*)d_in[12];
    const float* Wb     = (const float*)d_in[13];
    const float* bb     = (const float*)d_in[14];
    const float* head_w = (const float*)d_in[15];
    const float* Wout   = (const float*)d_in[16];
    const float* bout   = (const float*)d_in[17];
    float* out = (float*)d_out;
    float* ws  = (float*)d_ws;

    float* q    = ws;             // 768*192          = 147456
    float* kT   = ws + 147456;    // 12*768*16        = 147456
    float* kpT  = ws + 294912;    // 12*768*12        = 110592
    float* vall = ws + 405504;    // 768*480          = 368640
    float* qp   = ws + 774144;    // 768*144          = 110592
    float* qpr  = ws + 884736;    // 768*144          = 110592
    float* kvpr = ws + 995328;    // 768*432          = 331776
    float* cat  = ws + 1327104;   // 768*2112         = 1622016

    kproj<<<dim3(96, 9), 256, 0, stream>>>(s, Wq, bq, Wkv, bkv, Wqp, bqp, Wkvp, bkvp,
                                           q, kT, vall, qpr, kvpr);
    krot<<<dim3(768), 192, 0, stream>>>(rot, trans, qpr, kvpr, qp, kpT, vall);
    kattn<<<dim3(768), 256, 0, stream>>>(z, mask, Wb, bb, head_w, rot, trans,
                                         q, kT, kpT, vall, qp, cat);
    kout<<<dim3(96, 3), 256, 0, stream>>>(cat, Wout, bout, out);
}